// Round 6
// baseline (243.934 us; speedup 1.0000x reference)
//
#include <hip/hip_runtime.h>
#include <hip/hip_bf16.h>

typedef __attribute__((ext_vector_type(8))) short sh8;     // 8 bf16 (4 VGPRs)
typedef __attribute__((ext_vector_type(4))) float f32x4;   // MFMA C/D

#define LDC 136   // gemm epilogue C-tile stride in shorts
#define LDP 72    // P^T tile stride (shorts)
#define QSCALE 0.18033688f   // 0.125 * log2(e): folded into q at GEMM epilogue

#define EXP2F(x) __builtin_amdgcn_exp2f(x)   // v_exp_f32 (base-2), no libm wrapper

// async global->LDS DMA, 16B/lane; LDS dest = wave-uniform base + lane*16 (m104/m108)
__device__ __forceinline__ void glds16(const unsigned short* g, unsigned short* l){
  __builtin_amdgcn_global_load_lds(
      (const __attribute__((address_space(1))) unsigned int*)g,
      (__attribute__((address_space(3))) unsigned int*)l, 16, 0, 0);
}

__device__ __forceinline__ unsigned short f2bf(float f){
  union { float f; unsigned u; } c; c.f = f;
  unsigned u = c.u;
  u += 0x7fffu + ((u >> 16) & 1u);   // RNE
  return (unsigned short)(u >> 16);
}

__device__ __forceinline__ unsigned long long pack4bf(float a, float b, float c, float d){
  __hip_bfloat162 lo = __float22bfloat162_rn(make_float2(a, b));  // v_cvt_pk_bf16_f32
  __hip_bfloat162 hi = __float22bfloat162_rn(make_float2(c, d));
  union { unsigned u[2]; unsigned long long ull; } pk;
  pk.u[0] = *(unsigned*)&lo; pk.u[1] = *(unsigned*)&hi;
  return pk.ull;
}

// ---------------- fp32 -> bf16 elementwise ----------------
__global__ __launch_bounds__(256) void cvt_bf16(const float* __restrict__ src,
                                                unsigned short* __restrict__ dst, int n4){
  int i = blockIdx.x*256 + threadIdx.x;
  if (i < n4){
    float4 v = ((const float4*)src)[i];
    ushort4 o;
    o.x = f2bf(v.x); o.y = f2bf(v.y); o.z = f2bf(v.z); o.w = f2bf(v.w);
    ((ushort4*)dst)[i] = o;
  }
}

// ---------------- Wq/Wk/Wv (H,D,DH) -> Wt[j=jm*1024+h*64+e][d] bf16 (B^T layout) ----------------
__global__ __launch_bounds__(256) void transpose_w(const float* __restrict__ Wq,
                                                   const float* __restrict__ Wk,
                                                   const float* __restrict__ Wv,
                                                   unsigned short* __restrict__ wt){
  __shared__ float tile[64][65];
  int idx = blockIdx.x;            // 0..767 = 3 * 16(h) * 16(dt)
  int jm = idx >> 8;
  int rest = idx & 255;
  int h = rest >> 4, dt = rest & 15;
  const float* src = (jm==0 ? Wq : (jm==1 ? Wk : Wv)) + (size_t)h*65536;  // [D][64] slab
  int t = threadIdx.x;
  {
    int r = t >> 2, c0 = (t & 3)*16;
    for (int i=0;i<4;++i){
      float4 v = *(const float4*)&src[(size_t)(dt*64 + r)*64 + c0 + i*4];
      tile[r][c0+i*4+0]=v.x; tile[r][c0+i*4+1]=v.y; tile[r][c0+i*4+2]=v.z; tile[r][c0+i*4+3]=v.w;
    }
  }
  __syncthreads();
  {
    int e = t >> 2, r0 = (t & 3)*16;
    int j = jm*1024 + h*64 + e;
    __align__(16) unsigned short buf[16];
    for (int i=0;i<16;++i) buf[i] = f2bf(tile[r0+i][e]);
    *(uint4*)&wt[(size_t)j*1024 + dt*64 + r0    ] = *(uint4*)&buf[0];
    *(uint4*)&wt[(size_t)j*1024 + dt*64 + r0 + 8] = *(uint4*)&buf[8];
  }
}

// ---------------- GEMM C[M,N] = A[M,K] * Bt[N,K]^T, bf16 in / fp32 acc ----------------
// Staging via async global_load_lds(16B): LDS stride 64 (unpadded), XOR swizzle applied
// to the GLOBAL source chunk (LDS dest must be lane-contiguous); reads use chunk^(row&7).
// mode 0: N=3072 fused QKV -> q (pre-scaled by QSCALE), k [b][h][s][e]; v [b][h][e][s]
// mode 2: N=1024 -> Cf fp32 (final output)
__global__ __launch_bounds__(256) void gemm_bt(const unsigned short* __restrict__ A,
                                               const unsigned short* __restrict__ Bt,
                                               unsigned short* __restrict__ Cq,
                                               unsigned short* __restrict__ Ck,
                                               unsigned short* __restrict__ Cv,
                                               float* __restrict__ Cf,
                                               int M, int N, int K, int mode){
  __shared__ __align__(16) unsigned short smem[17408];   // max(2*128*64, 128*LDC) shorts
  unsigned short* As = smem;           // [128][64] xor-swizzled
  unsigned short* Bs = smem + 8192;
  const int t = threadIdx.x;
  const int w = t >> 6, lane = t & 63, l15 = lane & 15, quad = lane >> 4;

  // block swizzle: groups of 8 m-blocks share B-tiles in L2
  int lin = blockIdx.y * gridDim.x + blockIdx.x;
  int gn = gridDim.x, gm = gridDim.y;
  int per = 8 * gn;
  int gid = lin / per, rem = lin % per;
  int mfirst = gid * 8;
  int msz = (gm - mfirst) < 8 ? (gm - mfirst) : 8;
  const int m0 = (mfirst + rem % msz) * 128;
  const int n0 = (rem / msz) * 128;

  const int wm = (w >> 1)*64, wn = (w & 1)*64;
  const int lr8 = lane >> 3;              // row within the wave's 8-row staging group
  const int gc8 = (lane & 7) ^ lr8;       // swizzled global chunk this lane fetches
  const int h7 = l15 & 7;
  f32x4 acc[4][4] = {};

  for (int k0 = 0; k0 < K; k0 += 64){
    __syncthreads();
    for (int p = 0; p < 4; ++p){
      int rbase = p*32 + w*8;             // wave-uniform
      glds16(&A [(size_t)(m0 + rbase + lr8)*K + k0 + gc8*8], &As[rbase*64]);
      glds16(&Bt[(size_t)(n0 + rbase + lr8)*K + k0 + gc8*8], &Bs[rbase*64]);
    }
    __syncthreads();                      // compiler drains vmcnt before barrier
    for (int kk = 0; kk < 2; ++kk){
      const int cs = (((kk<<2) + quad) ^ h7) * 8;
      sh8 aF[4], bF[4];
      for (int i = 0; i < 4; ++i)
        aF[i] = *(const sh8*)&As[(wm + i*16 + l15)*64 + cs];
      for (int i = 0; i < 4; ++i)
        bF[i] = *(const sh8*)&Bs[(wn + i*16 + l15)*64 + cs];
      for (int mi = 0; mi < 4; ++mi)
        for (int ni = 0; ni < 4; ++ni)
          acc[mi][ni] = __builtin_amdgcn_mfma_f32_16x16x32_bf16(aF[mi], bF[ni], acc[mi][ni], 0, 0, 0);
    }
  }

  // C/D layout: col = lane&15, row = quad*4 + r (m89/m91-verified)
  if (mode == 2){
    for (int mi = 0; mi < 4; ++mi){
      int rowb = m0 + wm + mi*16 + quad*4;
      for (int ni = 0; ni < 4; ++ni){
        int col = n0 + wn + ni*16 + l15;
        for (int r = 0; r < 4; ++r)
          Cf[(size_t)(rowb + r)*N + col] = acc[mi][ni][r];
      }
    }
    return;
  }

  // mode 0: LDS round-trip epilogue. Ct = 128x136 shorts aliases smem.
  __syncthreads();
  unsigned short* Ct = smem;
  const bool isv = (n0 >= 2048);
  const float cscale = (n0 < 1024) ? QSCALE : 1.0f;   // fold softmax scale into q
  for (int mi = 0; mi < 4; ++mi){
    for (int ni = 0; ni < 4; ++ni){
      for (int r = 0; r < 4; ++r){
        int lr = wm + mi*16 + quad*4 + r;   // local m (s) index
        int lc = wn + ni*16 + l15;          // local n (col) index
        unsigned short bv = f2bf(acc[mi][ni][r] * cscale);
        if (isv) Ct[lc*LDC + lr] = bv;      // transposed for V
        else     Ct[lr*LDC + lc] = bv;
      }
    }
  }
  __syncthreads();

  const int b = m0 >> 11, sbase = m0 & 2047;
  const int hbase = (n0 & 1023) >> 6;
  if (!isv){
    unsigned short* dst = (n0 < 1024) ? Cq : Ck;
    for (int i = 0; i < 8; ++i){
      int s  = i*16 + (t >> 4);
      int hh = (t >> 3) & 1;
      int c  = t & 7;
      uint4 val = *(const uint4*)&Ct[s*LDC + hh*64 + c*8];
      int h = hbase + hh;
      *(uint4*)&dst[((size_t)(b*16 + h)*2048 + sbase + s)*64 + c*8] = val;
    }
  } else {
    for (int i = 0; i < 8; ++i){
      int ecol = i*16 + (t >> 4);
      int s0   = (t & 15)*8;
      uint4 val = *(const uint4*)&Ct[ecol*LDC + s0];
      int hh = ecol >> 6, e = ecol & 63;
      int h = hbase + hh;
      *(uint4*)&Cv[((size_t)(b*16 + h)*64 + e)*2048 + sbase + s0] = val;
    }
  }
}

// ---------------- flash attention: 2 q-strips/wave, 128 q-rows/block ----------------
// LDS-BW-bound fix: each wave's K/V fragment reads are shared across two 16-row q-strips,
// cutting LDS read traffic ~45% per unit work. Transposed-S, no-max softmax (R5-verified).
__global__ __launch_bounds__(256) void flash_attn(const unsigned short* __restrict__ q,
                                                  const unsigned short* __restrict__ k,
                                                  const unsigned short* __restrict__ vt,
                                                  const int* __restrict__ mask,
                                                  unsigned short* __restrict__ ctx){
  __shared__ __align__(16) unsigned short Ks[64*64];
  __shared__ __align__(16) unsigned short Vs[64*64];
  __shared__ __align__(16) unsigned short Ps[8][16*LDP];   // [wave*2+strip]
  __shared__ __align__(16) float kmadd[64];

  const int idx = blockIdx.x;
  const int qt = idx & 15, bh = idx >> 4;     // 16 consecutive blocks share (b,h)
  const int b = bh >> 4, h = bh & 15;
  const int t = threadIdx.x;
  const int w = t >> 6, lane = t & 63, l15 = lane & 15, quad = lane >> 4;
  const size_t base = (size_t)bh * 2048 * 64;

  // Q B-fragments for both strips straight from global (q pre-scaled by QSCALE)
  const unsigned short* qp0 = q + base + (size_t)(qt*128 + w*16 + l15)*64;
  sh8 qf[2][2];
  qf[0][0] = *(const sh8*)(qp0 +        quad*8);
  qf[0][1] = *(const sh8*)(qp0 +   32 + quad*8);
  qf[1][0] = *(const sh8*)(qp0 + 4096 +      quad*8);   // strip 1 = +64 rows
  qf[1][1] = *(const sh8*)(qp0 + 4096 + 32 + quad*8);

  const int sr = t >> 3, sc = t & 7;          // staging row / chunk
  const int h7 = l15 & 7;
  const int cs0 = ((quad    ) ^ h7) * 8;      // kk=0 swizzled chunk
  const int cs1 = ((quad + 4) ^ h7) * 8;      // kk=1

  float la[2][4] = {};
  f32x4 O[2][4] = {};   // O^T[strip][et]: row=quad*4+r=e, col=l15=qrow

  for (int kt = 0; kt < 32; ++kt){
    __syncthreads();
    { // stage K [key][e], V^T [e][key], xor-swizzled; key-mask adds
      for (int p = 0; p < 2; ++p){
        int r = sr + p*32;
        int pos = r*64 + (sc ^ (r & 7))*8;
        *(uint4*)&Ks[pos] = *(const uint4*)&k [base + (size_t)(kt*64 + r)*64 + sc*8];
        *(uint4*)&Vs[pos] = *(const uint4*)&vt[base + (size_t)r*2048 + kt*64 + sc*8];
      }
      if (t < 64) kmadd[t] = mask[b*2048 + kt*64 + t] ? 0.f : -1e30f;
    }
    __syncthreads();

    // S^T = K·Q^T for both strips; K-frags shared
    for (int mt = 0; mt < 4; ++mt){
      sh8 a0 = *(const sh8*)&Ks[(mt*16 + l15)*64 + cs0];
      sh8 a1 = *(const sh8*)&Ks[(mt*16 + l15)*64 + cs1];
      float4 km = *(const float4*)&kmadd[mt*16 + quad*4];
      #pragma unroll
      for (int st = 0; st < 2; ++st){
        f32x4 a{0.f,0.f,0.f,0.f};
        a = __builtin_amdgcn_mfma_f32_16x16x32_bf16(a0, qf[st][0], a, 0, 0, 0);
        a = __builtin_amdgcn_mfma_f32_16x16x32_bf16(a1, qf[st][1], a, 0, 0, 0);
        float e0 = EXP2F(a[0] + km.x); la[st][0] += e0;
        float e1 = EXP2F(a[1] + km.y); la[st][1] += e1;
        float e2 = EXP2F(a[2] + km.z); la[st][2] += e2;
        float e3 = EXP2F(a[3] + km.w); la[st][3] += e3;
        *(unsigned long long*)&Ps[w*2+st][l15*LDP + mt*16 + quad*4] = pack4bf(e0, e1, e2, e3);
      }
    }

    // O^T += V^T · P for both strips; V-frags shared
    sh8 pf[2][2];
    #pragma unroll
    for (int st = 0; st < 2; ++st){
      pf[st][0] = *(const sh8*)&Ps[w*2+st][l15*LDP +      quad*8];
      pf[st][1] = *(const sh8*)&Ps[w*2+st][l15*LDP + 32 + quad*8];
    }
    for (int et = 0; et < 4; ++et){
      sh8 vf0 = *(const sh8*)&Vs[(et*16 + l15)*64 + cs0];
      O[0][et] = __builtin_amdgcn_mfma_f32_16x16x32_bf16(vf0, pf[0][0], O[0][et], 0, 0, 0);
      O[1][et] = __builtin_amdgcn_mfma_f32_16x16x32_bf16(vf0, pf[1][0], O[1][et], 0, 0, 0);
    }
    for (int et = 0; et < 4; ++et){
      sh8 vf1 = *(const sh8*)&Vs[(et*16 + l15)*64 + cs1];
      O[0][et] = __builtin_amdgcn_mfma_f32_16x16x32_bf16(vf1, pf[0][1], O[0][et], 0, 0, 0);
      O[1][et] = __builtin_amdgcn_mfma_f32_16x16x32_bf16(vf1, pf[1][1], O[1][et], 0, 0, 0);
    }
  }

  // epilogue per strip: final l reduction, /l, query-mask zeroing
  #pragma unroll
  for (int st = 0; st < 2; ++st){
    float l_i = (la[st][0] + la[st][1]) + (la[st][2] + la[st][3]);
    l_i += __shfl_xor(l_i, 16);
    l_i += __shfl_xor(l_i, 32);
    int srow = qt*128 + st*64 + w*16 + l15;
    int qm = mask[b*2048 + srow];
    float inv = (qm && l_i > 0.f) ? 1.f/l_i : 0.f;
    unsigned short* crow = ctx + (((size_t)b*2048 + srow)*16 + h)*64;
    for (int et = 0; et < 4; ++et)
      *(unsigned long long*)&crow[et*16 + quad*4] =
        pack4bf(O[st][et][0]*inv, O[st][et][1]*inv, O[st][et][2]*inv, O[st][et][3]*inv);
  }
}

extern "C" void kernel_launch(void* const* d_in, const int* in_sizes, int n_in,
                              void* d_out, int out_size, void* d_ws, size_t ws_size,
                              hipStream_t stream){
  const float* x  = (const float*)d_in[0];
  const int* mask = (const int*)  d_in[1];
  const float* Wq = (const float*)d_in[2];
  const float* Wk = (const float*)d_in[3];
  const float* Wv = (const float*)d_in[4];
  const float* Wo = (const float*)d_in[5];
  float* out = (float*)d_out;

  char* ws = (char*)d_ws;                                  // total 48 MiB
  unsigned short* x_bf  = (unsigned short*)(ws);           //  8 MiB  [4096][1024]
  unsigned short* wt    = (unsigned short*)(ws + 8388608); //  6 MiB  [3072][1024] (QKV B^T)
  unsigned short* wo_bf = (unsigned short*)(ws + 14680064);//  2 MiB  [1024][1024]
  unsigned short* qb    = (unsigned short*)(ws + 16777216);//  8 MiB  [b][h][s][e] (pre-scaled)
  unsigned short* kb    = (unsigned short*)(ws + 25165824);//  8 MiB  [b][h][s][e]
  unsigned short* vtb   = (unsigned short*)(ws + 33554432);//  8 MiB  [b][h][e][s]
  unsigned short* ctx   = (unsigned short*)(ws + 41943040);//  8 MiB  [b][s][h*64+e]

  cvt_bf16<<<4096, 256, 0, stream>>>(x,  x_bf, 1048576);
  cvt_bf16<<<1024, 256, 0, stream>>>(Wo, wo_bf, 262144);
  transpose_w<<<768, 256, 0, stream>>>(Wq, Wk, Wv, wt);
  gemm_bt<<<dim3(24, 32), 256, 0, stream>>>(x_bf, wt, qb, kb, vtb, nullptr, 4096, 3072, 1024, 0);
  flash_attn<<<512, 256, 0, stream>>>(qb, kb, vtb, mask, ctx);
  gemm_bt<<<dim3(8, 32), 256, 0, stream>>>(ctx, wo_bf, nullptr, nullptr, nullptr, out, 4096, 1024, 1024, 2);
}

// Round 7
// 218.607 us; speedup vs baseline: 1.1159x; 1.1159x over previous
//
#include <hip/hip_runtime.h>
#include <hip/hip_bf16.h>

typedef __attribute__((ext_vector_type(8))) short sh8;     // 8 bf16 (4 VGPRs)
typedef __attribute__((ext_vector_type(4))) float f32x4;   // MFMA C/D

#define LDC 136   // gemm epilogue C-tile stride in shorts
#define LDP 72    // P^T tile stride (shorts)
#define QSCALE 0.18033688f   // 0.125 * log2(e): folded into q at GEMM epilogue

#define EXP2F(x) __builtin_amdgcn_exp2f(x)   // v_exp_f32 (base-2), no libm wrapper

// async global->LDS DMA, 16B/lane; LDS dest = wave-uniform base + lane*16 (m104/m108)
__device__ __forceinline__ void glds16(const unsigned short* g, unsigned short* l){
  __builtin_amdgcn_global_load_lds(
      (const __attribute__((address_space(1))) unsigned int*)g,
      (__attribute__((address_space(3))) unsigned int*)l, 16, 0, 0);
}

__device__ __forceinline__ unsigned short f2bf(float f){
  union { float f; unsigned u; } c; c.f = f;
  unsigned u = c.u;
  u += 0x7fffu + ((u >> 16) & 1u);   // RNE
  return (unsigned short)(u >> 16);
}

__device__ __forceinline__ unsigned long long pack4bf(float a, float b, float c, float d){
  __hip_bfloat162 lo = __float22bfloat162_rn(make_float2(a, b));  // v_cvt_pk_bf16_f32
  __hip_bfloat162 hi = __float22bfloat162_rn(make_float2(c, d));
  union { unsigned u[2]; unsigned long long ull; } pk;
  pk.u[0] = *(unsigned*)&lo; pk.u[1] = *(unsigned*)&hi;
  return pk.ull;
}

// ---------------- fp32 -> bf16 elementwise ----------------
__global__ __launch_bounds__(256) void cvt_bf16(const float* __restrict__ src,
                                                unsigned short* __restrict__ dst, int n4){
  int i = blockIdx.x*256 + threadIdx.x;
  if (i < n4){
    float4 v = ((const float4*)src)[i];
    ushort4 o;
    o.x = f2bf(v.x); o.y = f2bf(v.y); o.z = f2bf(v.z); o.w = f2bf(v.w);
    ((ushort4*)dst)[i] = o;
  }
}

// ---------------- Wq/Wk/Wv (H,D,DH) -> Wt[j=jm*1024+h*64+e][d] bf16 (B^T layout) ----------------
__global__ __launch_bounds__(256) void transpose_w(const float* __restrict__ Wq,
                                                   const float* __restrict__ Wk,
                                                   const float* __restrict__ Wv,
                                                   unsigned short* __restrict__ wt){
  __shared__ float tile[64][65];
  int idx = blockIdx.x;            // 0..767 = 3 * 16(h) * 16(dt)
  int jm = idx >> 8;
  int rest = idx & 255;
  int h = rest >> 4, dt = rest & 15;
  const float* src = (jm==0 ? Wq : (jm==1 ? Wk : Wv)) + (size_t)h*65536;  // [D][64] slab
  int t = threadIdx.x;
  {
    int r = t >> 2, c0 = (t & 3)*16;
    for (int i=0;i<4;++i){
      float4 v = *(const float4*)&src[(size_t)(dt*64 + r)*64 + c0 + i*4];
      tile[r][c0+i*4+0]=v.x; tile[r][c0+i*4+1]=v.y; tile[r][c0+i*4+2]=v.z; tile[r][c0+i*4+3]=v.w;
    }
  }
  __syncthreads();
  {
    int e = t >> 2, r0 = (t & 3)*16;
    int j = jm*1024 + h*64 + e;
    __align__(16) unsigned short buf[16];
    for (int i=0;i<16;++i) buf[i] = f2bf(tile[r0+i][e]);
    *(uint4*)&wt[(size_t)j*1024 + dt*64 + r0    ] = *(uint4*)&buf[0];
    *(uint4*)&wt[(size_t)j*1024 + dt*64 + r0 + 8] = *(uint4*)&buf[8];
  }
}

// ---------------- GEMM C[M,N] = A[M,K] * Bt[N,K]^T, bf16 in / fp32 acc ----------------
// Async glds16 staging; LDS stride 64 unpadded, XOR swizzle on the GLOBAL source chunk.
// mode 0: N=3072 fused QKV -> q (pre-scaled by QSCALE), k [b][h][s][e]; v [b][h][e][s]
// mode 2: N=1024 -> Cf fp32 (final output)
__global__ __launch_bounds__(256) void gemm_bt(const unsigned short* __restrict__ A,
                                               const unsigned short* __restrict__ Bt,
                                               unsigned short* __restrict__ Cq,
                                               unsigned short* __restrict__ Ck,
                                               unsigned short* __restrict__ Cv,
                                               float* __restrict__ Cf,
                                               int M, int N, int K, int mode){
  __shared__ __align__(16) unsigned short smem[17408];   // max(2*128*64, 128*LDC) shorts
  unsigned short* As = smem;           // [128][64] xor-swizzled
  unsigned short* Bs = smem + 8192;
  const int t = threadIdx.x;
  const int w = t >> 6, lane = t & 63, l15 = lane & 15, quad = lane >> 4;

  // block swizzle: groups of 8 m-blocks share B-tiles in L2
  int lin = blockIdx.y * gridDim.x + blockIdx.x;
  int gn = gridDim.x, gm = gridDim.y;
  int per = 8 * gn;
  int gid = lin / per, rem = lin % per;
  int mfirst = gid * 8;
  int msz = (gm - mfirst) < 8 ? (gm - mfirst) : 8;
  const int m0 = (mfirst + rem % msz) * 128;
  const int n0 = (rem / msz) * 128;

  const int wm = (w >> 1)*64, wn = (w & 1)*64;
  const int lr8 = lane >> 3;              // row within the wave's 8-row staging group
  const int gc8 = (lane & 7) ^ lr8;       // swizzled global chunk this lane fetches
  const int h7 = l15 & 7;
  f32x4 acc[4][4] = {};

  for (int k0 = 0; k0 < K; k0 += 64){
    __syncthreads();
    for (int p = 0; p < 4; ++p){
      int rbase = p*32 + w*8;             // wave-uniform
      glds16(&A [(size_t)(m0 + rbase + lr8)*K + k0 + gc8*8], &As[rbase*64]);
      glds16(&Bt[(size_t)(n0 + rbase + lr8)*K + k0 + gc8*8], &Bs[rbase*64]);
    }
    __syncthreads();                      // compiler drains vmcnt before barrier
    for (int kk = 0; kk < 2; ++kk){
      const int cs = (((kk<<2) + quad) ^ h7) * 8;
      sh8 aF[4], bF[4];
      for (int i = 0; i < 4; ++i)
        aF[i] = *(const sh8*)&As[(wm + i*16 + l15)*64 + cs];
      for (int i = 0; i < 4; ++i)
        bF[i] = *(const sh8*)&Bs[(wn + i*16 + l15)*64 + cs];
      for (int mi = 0; mi < 4; ++mi)
        for (int ni = 0; ni < 4; ++ni)
          acc[mi][ni] = __builtin_amdgcn_mfma_f32_16x16x32_bf16(aF[mi], bF[ni], acc[mi][ni], 0, 0, 0);
    }
  }

  // C/D layout: col = lane&15, row = quad*4 + r (m89/m91-verified)
  if (mode == 2){
    for (int mi = 0; mi < 4; ++mi){
      int rowb = m0 + wm + mi*16 + quad*4;
      for (int ni = 0; ni < 4; ++ni){
        int col = n0 + wn + ni*16 + l15;
        for (int r = 0; r < 4; ++r)
          Cf[(size_t)(rowb + r)*N + col] = acc[mi][ni][r];
      }
    }
    return;
  }

  // mode 0: LDS round-trip epilogue. Ct = 128x136 shorts aliases smem.
  __syncthreads();
  unsigned short* Ct = smem;
  const bool isv = (n0 >= 2048);
  const float cscale = (n0 < 1024) ? QSCALE : 1.0f;   // fold softmax scale into q
  for (int mi = 0; mi < 4; ++mi){
    for (int ni = 0; ni < 4; ++ni){
      for (int r = 0; r < 4; ++r){
        int lr = wm + mi*16 + quad*4 + r;   // local m (s) index
        int lc = wn + ni*16 + l15;          // local n (col) index
        unsigned short bv = f2bf(acc[mi][ni][r] * cscale);
        if (isv) Ct[lc*LDC + lr] = bv;      // transposed for V
        else     Ct[lr*LDC + lc] = bv;
      }
    }
  }
  __syncthreads();

  const int b = m0 >> 11, sbase = m0 & 2047;
  const int hbase = (n0 & 1023) >> 6;
  if (!isv){
    unsigned short* dst = (n0 < 1024) ? Cq : Ck;
    for (int i = 0; i < 8; ++i){
      int s  = i*16 + (t >> 4);
      int hh = (t >> 3) & 1;
      int c  = t & 7;
      uint4 val = *(const uint4*)&Ct[s*LDC + hh*64 + c*8];
      int h = hbase + hh;
      *(uint4*)&dst[((size_t)(b*16 + h)*2048 + sbase + s)*64 + c*8] = val;
    }
  } else {
    for (int i = 0; i < 8; ++i){
      int ecol = i*16 + (t >> 4);
      int s0   = (t & 15)*8;
      uint4 val = *(const uint4*)&Ct[ecol*LDC + s0];
      int hh = ecol >> 6, e = ecol & 63;
      int h = hbase + hh;
      *(uint4*)&Cv[((size_t)(b*16 + h)*64 + e)*2048 + sbase + s0] = val;
    }
  }
}

// ---------------- flash attention: 2 q-strips/wave + double-buffered K/V pipeline ----------------
// One barrier per kt: stage kt+1 (async glds16) right after the barrier, compute kt.
// The vmcnt drain the compiler emits before the NEXT barrier lands after a full compute
// phase, hiding global latency (the R6 regression was latency exposure at 2 blocks/CU).
// Mask preloaded once into LDS. XCD-aware swizzle: idx&7 owns 4 (b,h) -> 2MB K/V per L2.
__global__ __launch_bounds__(256) void flash_attn(const unsigned short* __restrict__ q,
                                                  const unsigned short* __restrict__ k,
                                                  const unsigned short* __restrict__ vt,
                                                  const int* __restrict__ mask,
                                                  unsigned short* __restrict__ ctx){
  __shared__ __align__(16) unsigned short Ks[2][4096];   // [buf][64 key][64 e] xor-swizzled
  __shared__ __align__(16) unsigned short Vs[2][4096];   // [buf][64 e][64 key] xor-swizzled
  __shared__ __align__(16) unsigned short Ps[8][16*LDP]; // [wave*2+strip]
  __shared__ __align__(16) float kmAll[2048];            // key-mask adds for this b

  const int idx = blockIdx.x;
  const int xcd = idx & 7, sub = idx >> 3;
  const int bh = xcd*4 + (sub & 3);           // 4 (b,h) per XCD -> K/V L2-resident
  const int qt = sub >> 2;                    // 0..15
  const int b = bh >> 4, h = bh & 15;
  const int t = threadIdx.x;
  const int w = t >> 6, lane = t & 63, l15 = lane & 15, quad = lane >> 4;
  const size_t base = (size_t)bh * 2048 * 64;

  // Q B-fragments for both strips straight from global (q pre-scaled by QSCALE)
  const unsigned short* qp0 = q + base + (size_t)(qt*128 + w*16 + l15)*64;
  sh8 qf[2][2];
  qf[0][0] = *(const sh8*)(qp0 +        quad*8);
  qf[0][1] = *(const sh8*)(qp0 +   32 + quad*8);
  qf[1][0] = *(const sh8*)(qp0 + 4096 +      quad*8);   // strip 1 = +64 rows
  qf[1][1] = *(const sh8*)(qp0 + 4096 + 32 + quad*8);

  { // preload mask -> kmAll (once)
    int4 m0 = ((const int4*)(mask + b*2048))[t*2];
    int4 m1 = ((const int4*)(mask + b*2048))[t*2 + 1];
    float* d = &kmAll[t*8];
    d[0] = m0.x ? 0.f : -1e30f; d[1] = m0.y ? 0.f : -1e30f;
    d[2] = m0.z ? 0.f : -1e30f; d[3] = m0.w ? 0.f : -1e30f;
    d[4] = m1.x ? 0.f : -1e30f; d[5] = m1.y ? 0.f : -1e30f;
    d[6] = m1.z ? 0.f : -1e30f; d[7] = m1.w ? 0.f : -1e30f;
  }

  const int lr8 = lane >> 3;              // staging row within 8-row group
  const int gc8 = (lane & 7) ^ lr8;       // swizzled global source chunk
  const int h7 = l15 & 7;
  const int cs0 = ((quad    ) ^ h7) * 8;  // kk=0 swizzled read chunk
  const int cs1 = ((quad + 4) ^ h7) * 8;  // kk=1

  // stage K/V tile kt into buffer bb: wave w covers rows w*16..w*16+15 (2 glds each)
  auto stageKV = [&](int kt, int bb){
    for (int p = 0; p < 2; ++p){
      int r0 = w*16 + p*8;                // wave-uniform LDS base row
      glds16(&k [base + (size_t)(kt*64 + r0 + lr8)*64 + gc8*8], &Ks[bb][r0*64]);
      glds16(&vt[base + (size_t)(r0 + lr8)*2048 + kt*64 + gc8*8], &Vs[bb][r0*64]);
    }
  };

  float la[2][4] = {};
  f32x4 O[2][4] = {};   // O^T[strip][et]: row=quad*4+r=e, col=l15=qrow

  stageKV(0, 0);
  for (int kt = 0; kt < 32; ++kt){
    const int bb = kt & 1;
    __syncthreads();                      // buf bb staged; prev compute done
    if (kt + 1 < 32) stageKV(kt + 1, bb ^ 1);   // async into other buffer

    // S^T = K·Q^T for both strips; K-frags shared
    for (int mt = 0; mt < 4; ++mt){
      sh8 a0 = *(const sh8*)&Ks[bb][(mt*16 + l15)*64 + cs0];
      sh8 a1 = *(const sh8*)&Ks[bb][(mt*16 + l15)*64 + cs1];
      float4 km = *(const float4*)&kmAll[kt*64 + mt*16 + quad*4];
      #pragma unroll
      for (int st = 0; st < 2; ++st){
        f32x4 a{0.f,0.f,0.f,0.f};
        a = __builtin_amdgcn_mfma_f32_16x16x32_bf16(a0, qf[st][0], a, 0, 0, 0);
        a = __builtin_amdgcn_mfma_f32_16x16x32_bf16(a1, qf[st][1], a, 0, 0, 0);
        float e0 = EXP2F(a[0] + km.x); la[st][0] += e0;
        float e1 = EXP2F(a[1] + km.y); la[st][1] += e1;
        float e2 = EXP2F(a[2] + km.z); la[st][2] += e2;
        float e3 = EXP2F(a[3] + km.w); la[st][3] += e3;
        *(unsigned long long*)&Ps[w*2+st][l15*LDP + mt*16 + quad*4] = pack4bf(e0, e1, e2, e3);
      }
    }

    // O^T += V^T · P for both strips; V-frags shared (Ps is per-wave: no barrier needed)
    sh8 pf[2][2];
    #pragma unroll
    for (int st = 0; st < 2; ++st){
      pf[st][0] = *(const sh8*)&Ps[w*2+st][l15*LDP +      quad*8];
      pf[st][1] = *(const sh8*)&Ps[w*2+st][l15*LDP + 32 + quad*8];
    }
    for (int et = 0; et < 4; ++et){
      sh8 vf0 = *(const sh8*)&Vs[bb][(et*16 + l15)*64 + cs0];
      O[0][et] = __builtin_amdgcn_mfma_f32_16x16x32_bf16(vf0, pf[0][0], O[0][et], 0, 0, 0);
      O[1][et] = __builtin_amdgcn_mfma_f32_16x16x32_bf16(vf0, pf[1][0], O[1][et], 0, 0, 0);
    }
    for (int et = 0; et < 4; ++et){
      sh8 vf1 = *(const sh8*)&Vs[bb][(et*16 + l15)*64 + cs1];
      O[0][et] = __builtin_amdgcn_mfma_f32_16x16x32_bf16(vf1, pf[0][1], O[0][et], 0, 0, 0);
      O[1][et] = __builtin_amdgcn_mfma_f32_16x16x32_bf16(vf1, pf[1][1], O[1][et], 0, 0, 0);
    }
  }

  // epilogue per strip: final l reduction, /l, query-mask zeroing
  #pragma unroll
  for (int st = 0; st < 2; ++st){
    float l_i = (la[st][0] + la[st][1]) + (la[st][2] + la[st][3]);
    l_i += __shfl_xor(l_i, 16);
    l_i += __shfl_xor(l_i, 32);
    int srow = qt*128 + st*64 + w*16 + l15;
    bool qm = (kmAll[srow] == 0.f);         // mask==1 -> add 0
    float inv = (qm && l_i > 0.f) ? 1.f/l_i : 0.f;
    unsigned short* crow = ctx + (((size_t)b*2048 + srow)*16 + h)*64;
    for (int et = 0; et < 4; ++et)
      *(unsigned long long*)&crow[et*16 + quad*4] =
        pack4bf(O[st][et][0]*inv, O[st][et][1]*inv, O[st][et][2]*inv, O[st][et][3]*inv);
  }
}

extern "C" void kernel_launch(void* const* d_in, const int* in_sizes, int n_in,
                              void* d_out, int out_size, void* d_ws, size_t ws_size,
                              hipStream_t stream){
  const float* x  = (const float*)d_in[0];
  const int* mask = (const int*)  d_in[1];
  const float* Wq = (const float*)d_in[2];
  const float* Wk = (const float*)d_in[3];
  const float* Wv = (const float*)d_in[4];
  const float* Wo = (const float*)d_in[5];
  float* out = (float*)d_out;

  char* ws = (char*)d_ws;                                  // total 48 MiB
  unsigned short* x_bf  = (unsigned short*)(ws);           //  8 MiB  [4096][1024]
  unsigned short* wt    = (unsigned short*)(ws + 8388608); //  6 MiB  [3072][1024] (QKV B^T)
  unsigned short* wo_bf = (unsigned short*)(ws + 14680064);//  2 MiB  [1024][1024]
  unsigned short* qb    = (unsigned short*)(ws + 16777216);//  8 MiB  [b][h][s][e] (pre-scaled)
  unsigned short* kb    = (unsigned short*)(ws + 25165824);//  8 MiB  [b][h][s][e]
  unsigned short* vtb   = (unsigned short*)(ws + 33554432);//  8 MiB  [b][h][e][s]
  unsigned short* ctx   = (unsigned short*)(ws + 41943040);//  8 MiB  [b][s][h*64+e]

  cvt_bf16<<<4096, 256, 0, stream>>>(x,  x_bf, 1048576);
  cvt_bf16<<<1024, 256, 0, stream>>>(Wo, wo_bf, 262144);
  transpose_w<<<768, 256, 0, stream>>>(Wq, Wk, Wv, wt);
  gemm_bt<<<dim3(24, 32), 256, 0, stream>>>(x_bf, wt, qb, kb, vtb, nullptr, 4096, 3072, 1024, 0);
  flash_attn<<<512, 256, 0, stream>>>(qb, kb, vtb, mask, ctx);
  gemm_bt<<<dim3(8, 32), 256, 0, stream>>>(ctx, wo_bf, nullptr, nullptr, nullptr, out, 4096, 1024, 1024, 2);
}

// Round 8
// 215.777 us; speedup vs baseline: 1.1305x; 1.0131x over previous
//
#include <hip/hip_runtime.h>
#include <hip/hip_bf16.h>

typedef __attribute__((ext_vector_type(8))) short sh8;     // 8 bf16 (4 VGPRs)
typedef __attribute__((ext_vector_type(4))) float f32x4;   // MFMA C/D

#define LDC 136   // gemm epilogue C-tile stride in shorts
#define QSCALE 0.18033688f   // 0.125 * log2(e): folded into q at GEMM epilogue
#define KMBF16 0xF14Au       // bf16(-1e30): exp2(score-1e30) == 0 exactly

#define EXP2F(x) __builtin_amdgcn_exp2f(x)   // v_exp_f32 (base-2), no libm wrapper

// async global->LDS DMA, 16B/lane; LDS dest = wave-uniform base + lane*16 (m104/m108)
__device__ __forceinline__ void glds16(const unsigned short* g, unsigned short* l){
  __builtin_amdgcn_global_load_lds(
      (const __attribute__((address_space(1))) unsigned int*)g,
      (__attribute__((address_space(3))) unsigned int*)l, 16, 0, 0);
}

__device__ __forceinline__ unsigned short f2bf(float f){
  union { float f; unsigned u; } c; c.f = f;
  unsigned u = c.u;
  u += 0x7fffu + ((u >> 16) & 1u);   // RNE
  return (unsigned short)(u >> 16);
}

__device__ __forceinline__ unsigned long long pack4bf(float a, float b, float c, float d){
  __hip_bfloat162 lo = __float22bfloat162_rn(make_float2(a, b));  // v_cvt_pk_bf16_f32
  __hip_bfloat162 hi = __float22bfloat162_rn(make_float2(c, d));
  union { unsigned u[2]; unsigned long long ull; } pk;
  pk.u[0] = *(unsigned*)&lo; pk.u[1] = *(unsigned*)&hi;
  return pk.ull;
}

// ---------------- fp32 -> bf16 elementwise (x and Wo fused in one launch) ----------------
__global__ __launch_bounds__(256) void cvt_bf16_2(const float* __restrict__ s0,
                                                  unsigned short* __restrict__ d0, int n0,
                                                  const float* __restrict__ s1,
                                                  unsigned short* __restrict__ d1, int n1){
  int i = blockIdx.x*256 + threadIdx.x;
  const float* s; unsigned short* d;
  if (i < n0){ s = s0; d = d0; }
  else if (i < n0 + n1){ s = s1; d = d1; i -= n0; }
  else return;
  float4 v = ((const float4*)s)[i];
  ushort4 o;
  o.x = f2bf(v.x); o.y = f2bf(v.y); o.z = f2bf(v.z); o.w = f2bf(v.w);
  ((ushort4*)d)[i] = o;
}

// ---------------- Wq/Wk/Wv (H,D,DH) -> Wt[j=jm*1024+h*64+e][d] bf16 (B^T layout) ----------------
__global__ __launch_bounds__(256) void transpose_w(const float* __restrict__ Wq,
                                                   const float* __restrict__ Wk,
                                                   const float* __restrict__ Wv,
                                                   unsigned short* __restrict__ wt){
  __shared__ float tile[64][65];
  int idx = blockIdx.x;            // 0..767 = 3 * 16(h) * 16(dt)
  int jm = idx >> 8;
  int rest = idx & 255;
  int h = rest >> 4, dt = rest & 15;
  const float* src = (jm==0 ? Wq : (jm==1 ? Wk : Wv)) + (size_t)h*65536;  // [D][64] slab
  int t = threadIdx.x;
  {
    int r = t >> 2, c0 = (t & 3)*16;
    for (int i=0;i<4;++i){
      float4 v = *(const float4*)&src[(size_t)(dt*64 + r)*64 + c0 + i*4];
      tile[r][c0+i*4+0]=v.x; tile[r][c0+i*4+1]=v.y; tile[r][c0+i*4+2]=v.z; tile[r][c0+i*4+3]=v.w;
    }
  }
  __syncthreads();
  {
    int e = t >> 2, r0 = (t & 3)*16;
    int j = jm*1024 + h*64 + e;
    __align__(16) unsigned short buf[16];
    for (int i=0;i<16;++i) buf[i] = f2bf(tile[r0+i][e]);
    *(uint4*)&wt[(size_t)j*1024 + dt*64 + r0    ] = *(uint4*)&buf[0];
    *(uint4*)&wt[(size_t)j*1024 + dt*64 + r0 + 8] = *(uint4*)&buf[8];
  }
}

// ---------------- GEMM C[M,N] = A[M,K] * Bt[N,K]^T, bf16 in / fp32 acc ----------------
// Async glds16 staging; LDS stride 64 unpadded, XOR swizzle on the GLOBAL source chunk.
// mode 0: N=3072 fused QKV -> q (pre-scaled by QSCALE), k [b][h][s][e]; v [b][h][e][s]
// mode 2: N=1024 -> Cf fp32 (final output)
__global__ __launch_bounds__(256) void gemm_bt(const unsigned short* __restrict__ A,
                                               const unsigned short* __restrict__ Bt,
                                               unsigned short* __restrict__ Cq,
                                               unsigned short* __restrict__ Ck,
                                               unsigned short* __restrict__ Cv,
                                               float* __restrict__ Cf,
                                               int M, int N, int K, int mode){
  __shared__ __align__(16) unsigned short smem[17408];   // max(2*128*64, 128*LDC) shorts
  unsigned short* As = smem;           // [128][64] xor-swizzled
  unsigned short* Bs = smem + 8192;
  const int t = threadIdx.x;
  const int w = t >> 6, lane = t & 63, l15 = lane & 15, quad = lane >> 4;

  // block swizzle: groups of 8 m-blocks share B-tiles in L2
  int lin = blockIdx.y * gridDim.x + blockIdx.x;
  int gn = gridDim.x, gm = gridDim.y;
  int per = 8 * gn;
  int gid = lin / per, rem = lin % per;
  int mfirst = gid * 8;
  int msz = (gm - mfirst) < 8 ? (gm - mfirst) : 8;
  const int m0 = (mfirst + rem % msz) * 128;
  const int n0 = (rem / msz) * 128;

  const int wm = (w >> 1)*64, wn = (w & 1)*64;
  const int lr8 = lane >> 3;              // row within the wave's 8-row staging group
  const int gc8 = (lane & 7) ^ lr8;       // swizzled global chunk this lane fetches
  const int h7 = l15 & 7;
  f32x4 acc[4][4] = {};

  for (int k0 = 0; k0 < K; k0 += 64){
    __syncthreads();
    for (int p = 0; p < 4; ++p){
      int rbase = p*32 + w*8;             // wave-uniform
      glds16(&A [(size_t)(m0 + rbase + lr8)*K + k0 + gc8*8], &As[rbase*64]);
      glds16(&Bt[(size_t)(n0 + rbase + lr8)*K + k0 + gc8*8], &Bs[rbase*64]);
    }
    __syncthreads();                      // compiler drains vmcnt before barrier
    for (int kk = 0; kk < 2; ++kk){
      const int cs = (((kk<<2) + quad) ^ h7) * 8;
      sh8 aF[4], bF[4];
      for (int i = 0; i < 4; ++i)
        aF[i] = *(const sh8*)&As[(wm + i*16 + l15)*64 + cs];
      for (int i = 0; i < 4; ++i)
        bF[i] = *(const sh8*)&Bs[(wn + i*16 + l15)*64 + cs];
      for (int mi = 0; mi < 4; ++mi)
        for (int ni = 0; ni < 4; ++ni)
          acc[mi][ni] = __builtin_amdgcn_mfma_f32_16x16x32_bf16(aF[mi], bF[ni], acc[mi][ni], 0, 0, 0);
    }
  }

  // C/D layout: col = lane&15, row = quad*4 + r (m89/m91-verified)
  if (mode == 2){
    for (int mi = 0; mi < 4; ++mi){
      int rowb = m0 + wm + mi*16 + quad*4;
      for (int ni = 0; ni < 4; ++ni){
        int col = n0 + wn + ni*16 + l15;
        for (int r = 0; r < 4; ++r)
          Cf[(size_t)(rowb + r)*N + col] = acc[mi][ni][r];
      }
    }
    return;
  }

  // mode 0: LDS round-trip epilogue. Ct = 128x136 shorts aliases smem.
  __syncthreads();
  unsigned short* Ct = smem;
  const bool isv = (n0 >= 2048);
  const float cscale = (n0 < 1024) ? QSCALE : 1.0f;   // fold softmax scale into q
  for (int mi = 0; mi < 4; ++mi){
    for (int ni = 0; ni < 4; ++ni){
      for (int r = 0; r < 4; ++r){
        int lr = wm + mi*16 + quad*4 + r;   // local m (s) index
        int lc = wn + ni*16 + l15;          // local n (col) index
        unsigned short bv = f2bf(acc[mi][ni][r] * cscale);
        if (isv) Ct[lc*LDC + lr] = bv;      // transposed for V
        else     Ct[lr*LDC + lc] = bv;
      }
    }
  }
  __syncthreads();

  const int b = m0 >> 11, sbase = m0 & 2047;
  const int hbase = (n0 & 1023) >> 6;
  if (!isv){
    unsigned short* dst = (n0 < 1024) ? Cq : Ck;
    for (int i = 0; i < 8; ++i){
      int s  = i*16 + (t >> 4);
      int hh = (t >> 3) & 1;
      int c  = t & 7;
      uint4 val = *(const uint4*)&Ct[s*LDC + hh*64 + c*8];
      int h = hbase + hh;
      *(uint4*)&dst[((size_t)(b*16 + h)*2048 + sbase + s)*64 + c*8] = val;
    }
  } else {
    for (int i = 0; i < 8; ++i){
      int ecol = i*16 + (t >> 4);
      int s0   = (t & 15)*8;
      uint4 val = *(const uint4*)&Ct[ecol*LDC + s0];
      int hh = ecol >> 6, e = ecol & 63;
      int h = hbase + hh;
      *(uint4*)&Cv[((size_t)(b*16 + h)*64 + e)*2048 + sbase + s0] = val;
    }
  }
}

// ---------------- flash attention: 2 q-strips/wave, dbuf K/V pipeline, 3 blocks/CU ----------------
// LDS 52.0 KB (< 54.6 = 160/3): kmAll stored as bf16 (mask add folded into the MFMA
// C-operand init -> deletes 32 v_add/kt), Ps XOR-swizzled stride 64 (no pad).
// One barrier per kt; stage kt+1 via async glds16 while computing kt (R7-verified).
// XCD-aware swizzle: idx&7 owns 4 (b,h) -> 2MB K/V resident per XCD L2 (R7: FETCH 70->12MB).
__global__ __launch_bounds__(256) void flash_attn(const unsigned short* __restrict__ q,
                                                  const unsigned short* __restrict__ k,
                                                  const unsigned short* __restrict__ vt,
                                                  const int* __restrict__ mask,
                                                  unsigned short* __restrict__ ctx){
  __shared__ __align__(16) unsigned short Ks[2][4096];   // [buf][64 key][64 e] xor-swizzled
  __shared__ __align__(16) unsigned short Vs[2][4096];   // [buf][64 e][64 key] xor-swizzled
  __shared__ __align__(16) unsigned short Ps[8][1024];   // [wave*2+strip][16 qrow][64 key] xor-swz
  __shared__ __align__(16) unsigned short kmb[2048];     // bf16 key-mask adds (0 or -1e30)

  const int idx = blockIdx.x;
  const int xcd = idx & 7, sub = idx >> 3;
  const int bh = xcd*4 + (sub & 3);           // 4 (b,h) per XCD -> K/V L2-resident
  const int qt = sub >> 2;                    // 0..15
  const int b = bh >> 4, h = bh & 15;
  const int t = threadIdx.x;
  const int w = t >> 6, lane = t & 63, l15 = lane & 15, quad = lane >> 4;
  const size_t base = (size_t)bh * 2048 * 64;

  // Q B-fragments for both strips straight from global (q pre-scaled by QSCALE)
  const unsigned short* qp0 = q + base + (size_t)(qt*128 + w*16 + l15)*64;
  sh8 qf[2][2];
  qf[0][0] = *(const sh8*)(qp0 +        quad*8);
  qf[0][1] = *(const sh8*)(qp0 +   32 + quad*8);
  qf[1][0] = *(const sh8*)(qp0 + 4096 +      quad*8);   // strip 1 = +64 rows
  qf[1][1] = *(const sh8*)(qp0 + 4096 + 32 + quad*8);

  { // preload mask -> kmb bf16 (once)
    int4 m0 = ((const int4*)(mask + b*2048))[t*2];
    int4 m1 = ((const int4*)(mask + b*2048))[t*2 + 1];
    __align__(16) unsigned short tmp[8];
    tmp[0] = m0.x ? 0 : KMBF16; tmp[1] = m0.y ? 0 : KMBF16;
    tmp[2] = m0.z ? 0 : KMBF16; tmp[3] = m0.w ? 0 : KMBF16;
    tmp[4] = m1.x ? 0 : KMBF16; tmp[5] = m1.y ? 0 : KMBF16;
    tmp[6] = m1.z ? 0 : KMBF16; tmp[7] = m1.w ? 0 : KMBF16;
    *(uint4*)&kmb[t*8] = *(uint4*)tmp;
  }

  const int lr8 = lane >> 3;              // staging row within 8-row group
  const int gc8 = (lane & 7) ^ lr8;       // swizzled global source chunk
  const int h7 = l15 & 7;
  const int cs0 = ((quad    ) ^ h7) * 8;  // kk=0 swizzled read chunk (K/V tiles)
  const int cs1 = ((quad + 4) ^ h7) * 8;  // kk=1
  // Ps swizzle: write chunk8 (mt*2+(quad>>1))^h7 (+ (quad&1)*4), read chunk8 (kk*4+quad)^h7
  const int pw_off = (quad & 1)*4;
  const int pr0 = ((0*4 + quad) ^ h7) * 8;
  const int pr1 = ((1*4 + quad) ^ h7) * 8;

  // stage K/V tile kt into buffer bb: wave w covers rows w*16..w*16+15 (2 glds each)
  auto stageKV = [&](int kt, int bb){
    for (int p = 0; p < 2; ++p){
      int r0 = w*16 + p*8;                // wave-uniform LDS base row
      glds16(&k [base + (size_t)(kt*64 + r0 + lr8)*64 + gc8*8], &Ks[bb][r0*64]);
      glds16(&vt[base + (size_t)(r0 + lr8)*2048 + kt*64 + gc8*8], &Vs[bb][r0*64]);
    }
  };

  float la[2][4] = {};
  f32x4 O[2][4] = {};   // O^T[strip][et]: row=quad*4+r=e, col=l15=qrow

  stageKV(0, 0);
  for (int kt = 0; kt < 32; ++kt){
    const int bb = kt & 1;
    __syncthreads();                      // buf bb staged; prev compute done
    if (kt + 1 < 32) stageKV(kt + 1, bb ^ 1);   // async into other buffer

    // S^T = K·Q^T + km (mask folded into the MFMA C-init); K-frags shared across strips
    for (int mt = 0; mt < 4; ++mt){
      sh8 a0 = *(const sh8*)&Ks[bb][(mt*16 + l15)*64 + cs0];
      sh8 a1 = *(const sh8*)&Ks[bb][(mt*16 + l15)*64 + cs1];
      unsigned long long kq = *(const unsigned long long*)&kmb[kt*64 + mt*16 + quad*4];
      unsigned d0 = (unsigned)kq, d1 = (unsigned)(kq >> 32);
      f32x4 cinit;
      cinit[0] = __uint_as_float(d0 << 16);
      cinit[1] = __uint_as_float(d0 & 0xFFFF0000u);
      cinit[2] = __uint_as_float(d1 << 16);
      cinit[3] = __uint_as_float(d1 & 0xFFFF0000u);
      const int pwc = (((mt*2 + (quad>>1)) ^ h7) * 8) + pw_off;
      #pragma unroll
      for (int st = 0; st < 2; ++st){
        f32x4 a = cinit;
        a = __builtin_amdgcn_mfma_f32_16x16x32_bf16(a0, qf[st][0], a, 0, 0, 0);
        a = __builtin_amdgcn_mfma_f32_16x16x32_bf16(a1, qf[st][1], a, 0, 0, 0);
        float e0 = EXP2F(a[0]); la[st][0] += e0;
        float e1 = EXP2F(a[1]); la[st][1] += e1;
        float e2 = EXP2F(a[2]); la[st][2] += e2;
        float e3 = EXP2F(a[3]); la[st][3] += e3;
        *(unsigned long long*)&Ps[w*2+st][l15*64 + pwc] = pack4bf(e0, e1, e2, e3);
      }
    }

    // O^T += V^T · P for both strips; V-frags shared (Ps per-wave: no barrier needed)
    sh8 pf[2][2];
    #pragma unroll
    for (int st = 0; st < 2; ++st){
      pf[st][0] = *(const sh8*)&Ps[w*2+st][l15*64 + pr0];
      pf[st][1] = *(const sh8*)&Ps[w*2+st][l15*64 + pr1];
    }
    for (int et = 0; et < 4; ++et){
      sh8 vf0 = *(const sh8*)&Vs[bb][(et*16 + l15)*64 + cs0];
      O[0][et] = __builtin_amdgcn_mfma_f32_16x16x32_bf16(vf0, pf[0][0], O[0][et], 0, 0, 0);
      O[1][et] = __builtin_amdgcn_mfma_f32_16x16x32_bf16(vf0, pf[1][0], O[1][et], 0, 0, 0);
    }
    for (int et = 0; et < 4; ++et){
      sh8 vf1 = *(const sh8*)&Vs[bb][(et*16 + l15)*64 + cs1];
      O[0][et] = __builtin_amdgcn_mfma_f32_16x16x32_bf16(vf1, pf[0][1], O[0][et], 0, 0, 0);
      O[1][et] = __builtin_amdgcn_mfma_f32_16x16x32_bf16(vf1, pf[1][1], O[1][et], 0, 0, 0);
    }
  }

  // epilogue per strip: final l reduction, /l, query-mask zeroing
  #pragma unroll
  for (int st = 0; st < 2; ++st){
    float l_i = (la[st][0] + la[st][1]) + (la[st][2] + la[st][3]);
    l_i += __shfl_xor(l_i, 16);
    l_i += __shfl_xor(l_i, 32);
    int srow = qt*128 + st*64 + w*16 + l15;
    bool qm = (kmb[srow] == 0);             // mask==1 -> add 0
    float inv = (qm && l_i > 0.f) ? 1.f/l_i : 0.f;
    unsigned short* crow = ctx + (((size_t)b*2048 + srow)*16 + h)*64;
    for (int et = 0; et < 4; ++et)
      *(unsigned long long*)&crow[et*16 + quad*4] =
        pack4bf(O[st][et][0]*inv, O[st][et][1]*inv, O[st][et][2]*inv, O[st][et][3]*inv);
  }
}

extern "C" void kernel_launch(void* const* d_in, const int* in_sizes, int n_in,
                              void* d_out, int out_size, void* d_ws, size_t ws_size,
                              hipStream_t stream){
  const float* x  = (const float*)d_in[0];
  const int* mask = (const int*)  d_in[1];
  const float* Wq = (const float*)d_in[2];
  const float* Wk = (const float*)d_in[3];
  const float* Wv = (const float*)d_in[4];
  const float* Wo = (const float*)d_in[5];
  float* out = (float*)d_out;

  char* ws = (char*)d_ws;                                  // total 48 MiB
  unsigned short* x_bf  = (unsigned short*)(ws);           //  8 MiB  [4096][1024]
  unsigned short* wt    = (unsigned short*)(ws + 8388608); //  6 MiB  [3072][1024] (QKV B^T)
  unsigned short* wo_bf = (unsigned short*)(ws + 14680064);//  2 MiB  [1024][1024]
  unsigned short* qb    = (unsigned short*)(ws + 16777216);//  8 MiB  [b][h][s][e] (pre-scaled)
  unsigned short* kb    = (unsigned short*)(ws + 25165824);//  8 MiB  [b][h][s][e]
  unsigned short* vtb   = (unsigned short*)(ws + 33554432);//  8 MiB  [b][h][e][s]
  unsigned short* ctx   = (unsigned short*)(ws + 41943040);//  8 MiB  [b][s][h*64+e]

  cvt_bf16_2<<<5120, 256, 0, stream>>>(x, x_bf, 1048576, Wo, wo_bf, 262144);
  transpose_w<<<768, 256, 0, stream>>>(Wq, Wk, Wv, wt);
  gemm_bt<<<dim3(24, 32), 256, 0, stream>>>(x_bf, wt, qb, kb, vtb, nullptr, 4096, 3072, 1024, 0);
  flash_attn<<<512, 256, 0, stream>>>(qb, kb, vtb, mask, ctx);
  gemm_bt<<<dim3(8, 32), 256, 0, stream>>>(ctx, wo_bf, nullptr, nullptr, nullptr, out, 4096, 1024, 1024, 2);
}